// Round 1
// baseline (4283.926 us; speedup 1.0000x reference)
//
#include <hip/hip_runtime.h>

#define N_NODES 100000
#define N_EDGES 1600000
// DIN=128, DH=128, DOUT=64

// ---------------- degree / dinv ----------------
__global__ __launch_bounds__(256) void k_init_deg(int* __restrict__ deg) {
    int i = blockIdx.x * 256 + threadIdx.x;
    if (i < N_NODES) deg[i] = 1;  // self-loop
}

__global__ __launch_bounds__(256) void k_count(const int* __restrict__ dst, int* __restrict__ deg) {
    int e = blockIdx.x * 256 + threadIdx.x;
    if (e < N_EDGES) atomicAdd(&deg[dst[e]], 1);
}

__global__ __launch_bounds__(256) void k_dinv(const int* __restrict__ deg, float* __restrict__ dinv) {
    int i = blockIdx.x * 256 + threadIdx.x;
    if (i < N_NODES) dinv[i] = rsqrtf((float)deg[i]);
}

// ---------------- GEMM1: hs = (x @ W1) * dinv[row]; agg seeded with self-loop ----------------
// 32 rows/block, W1 (128x128, 64KB) + x tile (32x128, 16KB) in LDS; 4x4 outputs/thread.
__global__ __launch_bounds__(256) void k_gemm1(const float* __restrict__ x, const float* __restrict__ W1,
                                               const float* __restrict__ dinv,
                                               float* __restrict__ hs, float* __restrict__ agg) {
    __shared__ float Wl[128 * 128];
    __shared__ float Xl[32 * 128];
    int t = threadIdx.x;
    int row0 = blockIdx.x * 32;
    {
        const float4* W4 = (const float4*)W1;
        float4* Wl4 = (float4*)Wl;
#pragma unroll
        for (int i = 0; i < 16; ++i) Wl4[t + i * 256] = W4[t + i * 256];
        const float4* x4 = (const float4*)(x + (long long)row0 * 128);
        float4* Xl4 = (float4*)Xl;
#pragma unroll
        for (int i = 0; i < 4; ++i) Xl4[t + i * 256] = x4[t + i * 256];
    }
    __syncthreads();
    int tc = t & 31;   // col group: cols tc*4..+3
    int tr = t >> 5;   // row group: rows tr*4..+3
    float acc[4][4] = {};
    for (int k = 0; k < 128; ++k) {
        float4 w = *(const float4*)&Wl[k * 128 + tc * 4];
#pragma unroll
        for (int r = 0; r < 4; ++r) {
            float xv = Xl[(tr * 4 + r) * 128 + k];
            acc[r][0] = fmaf(xv, w.x, acc[r][0]);
            acc[r][1] = fmaf(xv, w.y, acc[r][1]);
            acc[r][2] = fmaf(xv, w.z, acc[r][2]);
            acc[r][3] = fmaf(xv, w.w, acc[r][3]);
        }
    }
#pragma unroll
    for (int r = 0; r < 4; ++r) {
        int row = row0 + tr * 4 + r;
        float s = dinv[row];
        float4 v = make_float4(acc[r][0] * s, acc[r][1] * s, acc[r][2] * s, acc[r][3] * s);
        ((float4*)(hs + (long long)row * 128))[tc] = v;
        ((float4*)(agg + (long long)row * 128))[tc] = v;  // self-loop seed
    }
}

// ---------------- edge scatter: agg[dst] += h[src], V float4 lanes per edge ----------------
template <int V, int SHIFT>
__global__ __launch_bounds__(256) void k_scatter(const int* __restrict__ src, const int* __restrict__ dst,
                                                 const float* __restrict__ h, float* __restrict__ agg) {
    int gid = blockIdx.x * 256 + threadIdx.x;
    int e = gid >> SHIFT;
    int lane = gid & (V - 1);
    if (e >= N_EDGES) return;
    int s = src[e], d = dst[e];
    float4 v = ((const float4*)(h + (long long)s * (V * 4)))[lane];
    float* ap = agg + (long long)d * (V * 4) + lane * 4;
    unsafeAtomicAdd(ap + 0, v.x);
    unsafeAtomicAdd(ap + 1, v.y);
    unsafeAtomicAdd(ap + 2, v.z);
    unsafeAtomicAdd(ap + 3, v.w);
}

// ---------------- layer1 epilogue + GEMM2: h=relu(dinv*agg1+b1); gs=(h@W2)*dinv ----------------
__global__ __launch_bounds__(256) void k_l2(const float* __restrict__ agg1, const float* __restrict__ b1,
                                            const float* __restrict__ W2, const float* __restrict__ dinv,
                                            float* __restrict__ gs, float* __restrict__ agg2) {
    __shared__ float Wl[128 * 64];   // 32KB
    __shared__ float Hl[32 * 132];   // padded stride: banks spread
    int t = threadIdx.x;
    int row0 = blockIdx.x * 32;
    {
        const float4* W4 = (const float4*)W2;
        float4* Wl4 = (float4*)Wl;
#pragma unroll
        for (int i = 0; i < 8; ++i) Wl4[t + i * 256] = W4[t + i * 256];
    }
#pragma unroll
    for (int i = t; i < 1024; i += 256) {  // 32 rows x 32 float4
        int r = i >> 5, c4 = i & 31;
        float4 a = ((const float4*)(agg1 + (long long)(row0 + r) * 128))[c4];
        float dv = dinv[row0 + r];
        float4 bb = ((const float4*)b1)[c4];
        float4 h;
        h.x = fmaxf(fmaf(dv, a.x, bb.x), 0.f);
        h.y = fmaxf(fmaf(dv, a.y, bb.y), 0.f);
        h.z = fmaxf(fmaf(dv, a.z, bb.z), 0.f);
        h.w = fmaxf(fmaf(dv, a.w, bb.w), 0.f);
        *(float4*)&Hl[r * 132 + c4 * 4] = h;
    }
    __syncthreads();
    int tc = t & 15;   // cols tc*4..+3 (of 64)
    int tr = t >> 4;   // rows tr*2..+1
    float acc[2][4] = {};
    for (int c = 0; c < 128; ++c) {
        float4 w = *(const float4*)&Wl[c * 64 + tc * 4];
#pragma unroll
        for (int r = 0; r < 2; ++r) {
            float hv = Hl[(tr * 2 + r) * 132 + c];
            acc[r][0] = fmaf(hv, w.x, acc[r][0]);
            acc[r][1] = fmaf(hv, w.y, acc[r][1]);
            acc[r][2] = fmaf(hv, w.z, acc[r][2]);
            acc[r][3] = fmaf(hv, w.w, acc[r][3]);
        }
    }
#pragma unroll
    for (int r = 0; r < 2; ++r) {
        int row = row0 + tr * 2 + r;
        float s = dinv[row];
        float4 v = make_float4(acc[r][0] * s, acc[r][1] * s, acc[r][2] * s, acc[r][3] * s);
        ((float4*)(gs + (long long)row * 64))[tc] = v;
        ((float4*)(agg2 + (long long)row * 64))[tc] = v;  // self-loop seed
    }
}

// ---------------- final: out = dinv[row]*agg2 + b2 ----------------
__global__ __launch_bounds__(256) void k_finish2(const float* __restrict__ agg2, const float* __restrict__ b2,
                                                 const float* __restrict__ dinv, float* __restrict__ out) {
    int i = blockIdx.x * 256 + threadIdx.x;  // over N*16 float4
    if (i >= N_NODES * 16) return;
    int r = i >> 4, c4 = i & 15;
    float4 a = ((const float4*)agg2)[i];
    float dv = dinv[r];
    float4 bb = ((const float4*)b2)[c4];
    float4 o = make_float4(fmaf(dv, a.x, bb.x), fmaf(dv, a.y, bb.y),
                           fmaf(dv, a.z, bb.z), fmaf(dv, a.w, bb.w));
    ((float4*)out)[i] = o;
}

extern "C" void kernel_launch(void* const* d_in, const int* in_sizes, int n_in,
                              void* d_out, int out_size, void* d_ws, size_t ws_size,
                              hipStream_t stream) {
    const float* x  = (const float*)d_in[0];
    const float* W1 = (const float*)d_in[1];
    const float* b1 = (const float*)d_in[2];
    const float* W2 = (const float*)d_in[3];
    const float* b2 = (const float*)d_in[4];
    const int*   ei = (const int*)d_in[5];   // per harness contract: integer -> const int*
    const int* src = ei;
    const int* dst = ei + N_EDGES;
    float* out = (float*)d_out;

    char* ws = (char*)d_ws;
    int*   deg  = (int*)ws;                          // 400 KB
    float* dinv = (float*)(ws + (512ll << 10));      // 400 KB
    float* hs1  = (float*)(ws + (1ll << 20));        // 51.2 MB
    float* agg1 = (float*)(ws + (53ll << 20));       // 51.2 MB
    float* gs   = (float*)(ws + (1ll << 20));        // reuse hs1 region, 25.6 MB
    float* agg2 = (float*)(ws + (27ll << 20));       // reuse hs1 region, 25.6 MB

    k_init_deg<<<(N_NODES + 255) / 256, 256, 0, stream>>>(deg);
    k_count<<<(N_EDGES + 255) / 256, 256, 0, stream>>>(dst, deg);
    k_dinv<<<(N_NODES + 255) / 256, 256, 0, stream>>>(deg, dinv);

    k_gemm1<<<N_NODES / 32, 256, 0, stream>>>(x, W1, dinv, hs1, agg1);
    k_scatter<32, 5><<<(N_EDGES * 32) / 256, 256, 0, stream>>>(src, dst, hs1, agg1);
    k_l2<<<N_NODES / 32, 256, 0, stream>>>(agg1, b1, W2, dinv, gs, agg2);
    k_scatter<16, 4><<<(N_EDGES * 16) / 256, 256, 0, stream>>>(src, dst, gs, agg2);
    k_finish2<<<(N_NODES * 16) / 256, 256, 0, stream>>>(agg2, b2, dinv, out);
}

// Round 2
// 580.586 us; speedup vs baseline: 7.3786x; 7.3786x over previous
//
#include <hip/hip_runtime.h>

#define N_NODES 100000
#define N_EDGES 1600000
// DIN=128, DH=128, DOUT=64
#define SCAN_BLOCKS 98   // ceil(100000/1024)

// ---------------- histogram / dinv ----------------
__global__ __launch_bounds__(256) void k_zero(int* __restrict__ indeg) {
    int i = blockIdx.x * 256 + threadIdx.x;
    if (i < N_NODES) indeg[i] = 0;
}

__global__ __launch_bounds__(256) void k_count(const int* __restrict__ dst, int* __restrict__ indeg) {
    int e = blockIdx.x * 256 + threadIdx.x;
    if (e < N_EDGES) atomicAdd(&indeg[dst[e]], 1);
}

__global__ __launch_bounds__(256) void k_dinv(const int* __restrict__ indeg, float* __restrict__ dinv) {
    int i = blockIdx.x * 256 + threadIdx.x;
    if (i < N_NODES) dinv[i] = rsqrtf(1.0f + (float)indeg[i]);  // +1 = self loop
}

// ---------------- exclusive scan (rowptr) ----------------
// pass 1: 1024 elems/block (256 thr x 4), block-local exclusive offsets + block sums
__global__ __launch_bounds__(256) void k_scan1(const int* __restrict__ indeg, int* __restrict__ rowptr,
                                               int* __restrict__ bsums) {
    __shared__ int sh[256];
    int t = threadIdx.x;
    int base = blockIdx.x * 1024 + t * 4;
    int v0 = (base + 0 < N_NODES) ? indeg[base + 0] : 0;
    int v1 = (base + 1 < N_NODES) ? indeg[base + 1] : 0;
    int v2 = (base + 2 < N_NODES) ? indeg[base + 2] : 0;
    int v3 = (base + 3 < N_NODES) ? indeg[base + 3] : 0;
    int s = v0 + v1 + v2 + v3;
    sh[t] = s;
    __syncthreads();
    for (int off = 1; off < 256; off <<= 1) {
        int u = (t >= off) ? sh[t - off] : 0;
        __syncthreads();
        sh[t] += u;
        __syncthreads();
    }
    int excl = sh[t] - s;
    if (t == 255) bsums[blockIdx.x] = sh[t];
    int o = excl;
    if (base + 0 < N_NODES) rowptr[base + 0] = o; o += v0;
    if (base + 1 < N_NODES) rowptr[base + 1] = o; o += v1;
    if (base + 2 < N_NODES) rowptr[base + 2] = o; o += v2;
    if (base + 3 < N_NODES) rowptr[base + 3] = o;
}

// pass 2: single block scans the 98 block sums (exclusive)
__global__ __launch_bounds__(128) void k_scan2(int* __restrict__ bsums) {
    __shared__ int sh[128];
    int t = threadIdx.x;
    int v = (t < SCAN_BLOCKS) ? bsums[t] : 0;
    sh[t] = v;
    __syncthreads();
    for (int off = 1; off < 128; off <<= 1) {
        int u = (t >= off) ? sh[t - off] : 0;
        __syncthreads();
        sh[t] += u;
        __syncthreads();
    }
    if (t < SCAN_BLOCKS) bsums[t] = sh[t] - v;
}

// pass 3: add block base, init cursor, set rowptr[N]
__global__ __launch_bounds__(256) void k_scan3(int* __restrict__ rowptr, int* __restrict__ cursor,
                                               const int* __restrict__ bsums) {
    int i = blockIdx.x * 256 + threadIdx.x;
    if (i < N_NODES) {
        int r = rowptr[i] + bsums[i >> 10];
        rowptr[i] = r;
        cursor[i] = r;
    }
    if (i == 0) rowptr[N_NODES] = N_EDGES;
}

// ---------------- CSR fill ----------------
__global__ __launch_bounds__(256) void k_fill(const int* __restrict__ src, const int* __restrict__ dst,
                                              int* __restrict__ cursor, int* __restrict__ csr) {
    int e = blockIdx.x * 256 + threadIdx.x;
    if (e < N_EDGES) {
        int pos = atomicAdd(&cursor[dst[e]], 1);
        csr[pos] = src[e];
    }
}

// ---------------- GEMM1: hs = (x @ W1) * dinv[row] ----------------
__global__ __launch_bounds__(256) void k_gemm1(const float* __restrict__ x, const float* __restrict__ W1,
                                               const float* __restrict__ dinv, float* __restrict__ hs) {
    __shared__ float Wl[128 * 128];
    __shared__ float Xl[32 * 128];
    int t = threadIdx.x;
    int row0 = blockIdx.x * 32;
    {
        const float4* W4 = (const float4*)W1;
        float4* Wl4 = (float4*)Wl;
#pragma unroll
        for (int i = 0; i < 16; ++i) Wl4[t + i * 256] = W4[t + i * 256];
        const float4* x4 = (const float4*)(x + (long long)row0 * 128);
        float4* Xl4 = (float4*)Xl;
#pragma unroll
        for (int i = 0; i < 4; ++i) Xl4[t + i * 256] = x4[t + i * 256];
    }
    __syncthreads();
    int tc = t & 31;
    int tr = t >> 5;
    float acc[4][4] = {};
    for (int k = 0; k < 128; ++k) {
        float4 w = *(const float4*)&Wl[k * 128 + tc * 4];
#pragma unroll
        for (int r = 0; r < 4; ++r) {
            float xv = Xl[(tr * 4 + r) * 128 + k];
            acc[r][0] = fmaf(xv, w.x, acc[r][0]);
            acc[r][1] = fmaf(xv, w.y, acc[r][1]);
            acc[r][2] = fmaf(xv, w.z, acc[r][2]);
            acc[r][3] = fmaf(xv, w.w, acc[r][3]);
        }
    }
#pragma unroll
    for (int r = 0; r < 4; ++r) {
        int row = row0 + tr * 4 + r;
        float s = dinv[row];
        float4 v = make_float4(acc[r][0] * s, acc[r][1] * s, acc[r][2] * s, acc[r][3] * s);
        ((float4*)(hs + (long long)row * 128))[tc] = v;
    }
}

// ---------------- aggregate layer 1: h = relu(dinv*(hs[n] + sum hs[nbr]) + b1) ----------------
// one wave per node; lane l covers cols [2l, 2l+1]
__global__ __launch_bounds__(256) void k_agg1(const float* __restrict__ hs, const int* __restrict__ rowptr,
                                              const int* __restrict__ csr, const float* __restrict__ dinv,
                                              const float* __restrict__ b1, float* __restrict__ h) {
    int n = (blockIdx.x * 256 + threadIdx.x) >> 6;
    int lane = threadIdx.x & 63;
    if (n >= N_NODES) return;
    float2 acc = ((const float2*)(hs + (long long)n * 128))[lane];  // self-loop seed
    int k = rowptr[n], end = rowptr[n + 1];
    for (; k + 1 < end; k += 2) {
        int s0 = csr[k], s1 = csr[k + 1];
        float2 a = ((const float2*)(hs + (long long)s0 * 128))[lane];
        float2 b = ((const float2*)(hs + (long long)s1 * 128))[lane];
        acc.x += a.x + b.x;
        acc.y += a.y + b.y;
    }
    if (k < end) {
        int s0 = csr[k];
        float2 a = ((const float2*)(hs + (long long)s0 * 128))[lane];
        acc.x += a.x;
        acc.y += a.y;
    }
    float dv = dinv[n];
    float2 bb = ((const float2*)b1)[lane];
    float2 o;
    o.x = fmaxf(fmaf(dv, acc.x, bb.x), 0.f);
    o.y = fmaxf(fmaf(dv, acc.y, bb.y), 0.f);
    ((float2*)(h + (long long)n * 128))[lane] = o;
}

// ---------------- GEMM2: gs = (h @ W2) * dinv[row] ----------------
__global__ __launch_bounds__(256) void k_gemm2(const float* __restrict__ h, const float* __restrict__ W2,
                                               const float* __restrict__ dinv, float* __restrict__ gs) {
    __shared__ float Wl[128 * 64];
    __shared__ float Hl[32 * 132];
    int t = threadIdx.x;
    int row0 = blockIdx.x * 32;
    {
        const float4* W4 = (const float4*)W2;
        float4* Wl4 = (float4*)Wl;
#pragma unroll
        for (int i = 0; i < 8; ++i) Wl4[t + i * 256] = W4[t + i * 256];
    }
#pragma unroll
    for (int i = t; i < 1024; i += 256) {
        int r = i >> 5, c4 = i & 31;
        float4 a = ((const float4*)(h + (long long)(row0 + r) * 128))[c4];
        *(float4*)&Hl[r * 132 + c4 * 4] = a;
    }
    __syncthreads();
    int tc = t & 15;
    int tr = t >> 4;
    float acc[2][4] = {};
    for (int c = 0; c < 128; ++c) {
        float4 w = *(const float4*)&Wl[c * 64 + tc * 4];
#pragma unroll
        for (int r = 0; r < 2; ++r) {
            float hv = Hl[(tr * 2 + r) * 132 + c];
            acc[r][0] = fmaf(hv, w.x, acc[r][0]);
            acc[r][1] = fmaf(hv, w.y, acc[r][1]);
            acc[r][2] = fmaf(hv, w.z, acc[r][2]);
            acc[r][3] = fmaf(hv, w.w, acc[r][3]);
        }
    }
#pragma unroll
    for (int r = 0; r < 2; ++r) {
        int row = row0 + tr * 2 + r;
        float s = dinv[row];
        float4 v = make_float4(acc[r][0] * s, acc[r][1] * s, acc[r][2] * s, acc[r][3] * s);
        ((float4*)(gs + (long long)row * 64))[tc] = v;
    }
}

// ---------------- aggregate layer 2: out = dinv*(gs[n] + sum gs[nbr]) + b2 ----------------
// one wave per node; lane l covers col l (64 cols)
__global__ __launch_bounds__(256) void k_agg2(const float* __restrict__ gs, const int* __restrict__ rowptr,
                                              const int* __restrict__ csr, const float* __restrict__ dinv,
                                              const float* __restrict__ b2, float* __restrict__ out) {
    int n = (blockIdx.x * 256 + threadIdx.x) >> 6;
    int lane = threadIdx.x & 63;
    if (n >= N_NODES) return;
    float acc = gs[(long long)n * 64 + lane];  // self-loop seed
    int k = rowptr[n], end = rowptr[n + 1];
    for (; k + 1 < end; k += 2) {
        int s0 = csr[k], s1 = csr[k + 1];
        float a = gs[(long long)s0 * 64 + lane];
        float b = gs[(long long)s1 * 64 + lane];
        acc += a + b;
    }
    if (k < end) acc += gs[(long long)csr[k] * 64 + lane];
    out[(long long)n * 64 + lane] = fmaf(dinv[n], acc, b2[lane]);
}

extern "C" void kernel_launch(void* const* d_in, const int* in_sizes, int n_in,
                              void* d_out, int out_size, void* d_ws, size_t ws_size,
                              hipStream_t stream) {
    const float* x  = (const float*)d_in[0];
    const float* W1 = (const float*)d_in[1];
    const float* b1 = (const float*)d_in[2];
    const float* W2 = (const float*)d_in[3];
    const float* b2 = (const float*)d_in[4];
    const int*   ei = (const int*)d_in[5];
    const int* src = ei;
    const int* dst = ei + N_EDGES;
    float* out = (float*)d_out;

    char* ws = (char*)d_ws;
    int*   csr    = (int*)(ws + 0);             // 6.4 MB
    int*   indeg  = (int*)(ws + 6400000);       // 400 KB
    int*   rowptr = (int*)(ws + 6800000);       // 400 KB + 4
    int*   cursor = (int*)(ws + 7200256);       // 400 KB
    float* dinv   = (float*)(ws + 7600256);     // 400 KB
    int*   bsums  = (int*)(ws + 8000256);       // tiny
    float* hs     = (float*)(ws + 8388608);     // 51.2 MB  (also gs later)
    float* h      = (float*)(ws + 59588608);    // 51.2 MB
    float* gs     = hs;                          // hs dead after k_agg1

    k_zero<<<(N_NODES + 255) / 256, 256, 0, stream>>>(indeg);
    k_count<<<(N_EDGES + 255) / 256, 256, 0, stream>>>(dst, indeg);
    k_dinv<<<(N_NODES + 255) / 256, 256, 0, stream>>>(indeg, dinv);
    k_scan1<<<SCAN_BLOCKS, 256, 0, stream>>>(indeg, rowptr, bsums);
    k_scan2<<<1, 128, 0, stream>>>(bsums);
    k_scan3<<<(N_NODES + 255) / 256, 256, 0, stream>>>(rowptr, cursor, bsums);
    k_fill<<<(N_EDGES + 255) / 256, 256, 0, stream>>>(src, dst, cursor, csr);

    k_gemm1<<<N_NODES / 32, 256, 0, stream>>>(x, W1, dinv, hs);
    k_agg1<<<(N_NODES * 64) / 256, 256, 0, stream>>>(hs, rowptr, csr, dinv, b1, h);
    k_gemm2<<<N_NODES / 32, 256, 0, stream>>>(h, W2, dinv, gs);
    k_agg2<<<(N_NODES * 64) / 256, 256, 0, stream>>>(gs, rowptr, csr, dinv, b2, out);
}